// Round 17
// baseline (124.746 us; speedup 1.0000x reference)
//
#include <hip/hip_runtime.h>
#include <hip/hip_bf16.h>

// ---- problem constants ----
#define N_GAUSS 4096
#define N_PTS   32768
#define BLOCK   256
#define NSLICE  64                  // per-pb list split into 64 equal slices
#define NBLK_PT 128                 // 128 x 256 = 32768 points
#define GSTRIDE 32                  // floats per packed gaussian = 8 x float4
#define NCELL   4096                // 16^3 morton cells

#define SH_C0  0.28209479177387814f
#define SH_C1  0.4886025119029199f

// Workspace layout (float index):
#define WS_GP     0                          // 4096*32 = 131072 floats
#define WS_GHIST  131072                     // int[4096]
#define WS_CELLID 135168                     // int[32768]
#define WS_SPTS   167936                     // float4[32768] (16B aligned)
#define WS_ACC    299008                     // float[65536]
#define WS_GCOUNT 364544                     // int[128] (padded 256)
#define WS_GLIST  364800                     // int[128*4096]
// total 889,088 floats = 3.56 MB

__device__ __forceinline__ int cell_of(float x, float y, float z) {
    int cx = min(15, max(0, (int)((x + 3.2f) * 2.5f)));
    int cy = min(15, max(0, (int)((y + 3.2f) * 2.5f)));
    int cz = min(15, max(0, (int)((z + 3.2f) * 2.5f)));
    int ex = (cx & 1) | ((cx & 2) << 2) | ((cx & 4) << 4) | ((cx & 8) << 6);
    int ey = (cy & 1) | ((cy & 2) << 2) | ((cy & 4) << 4) | ((cy & 8) << 6);
    int ez = (cz & 1) | ((cz & 2) << 2) | ((cz & 4) << 4) | ((cz & 8) << 6);
    return ex | (ey << 1) | (ez << 2);
}

// ---------------------------------------------------------------------------
// N1 (7 blocks x 1024): block 0 bin+scan -> ghist; blocks 1-4 gaussian prep;
// blocks 5-6 zero acc.  (R16-proven)
// Record: q0=(cx,cy,cz,Tg) q1=(pxx,pxy,pxz,pyy) q2=(pyz,pzz,lnop,0)
//         q3..q6 = SH (constants pre-multiplied), q7 = pad
// ---------------------------------------------------------------------------
__global__ __launch_bounds__(1024) void setup_kernel(
    const float* __restrict__ pts, const float* __restrict__ xyz,
    const float* __restrict__ sh_dc, const float* __restrict__ sh_rest,
    const float* __restrict__ scaling, const float* __restrict__ rotation,
    const float* __restrict__ opl, float* __restrict__ gp,
    int* __restrict__ cellid, int* __restrict__ ghist, float* __restrict__ acc)
{
    const int t = threadIdx.x, bx = blockIdx.x;

    if (bx >= 5) {
        float4* a4 = (float4*)acc;
        int base = (bx - 5) * 1024 * 8 + t;
        #pragma unroll
        for (int i = 0; i < 8; ++i) a4[base + i * 1024] = make_float4(0.f, 0.f, 0.f, 0.f);
        return;
    }
    if (bx > 0) {
        int g = (bx - 1) * 1024 + t;
        float s0 = scaling[3*g+0], s1 = scaling[3*g+1], s2 = scaling[3*g+2];
        float i0 = __expf(-2.0f * s0);
        float i1 = __expf(-2.0f * s1);
        float i2 = __expf(-2.0f * s2);
        float maxs2 = __expf(2.0f * fmaxf(s0, fmaxf(s1, s2)));

        float r = rotation[4*g+0], x = rotation[4*g+1];
        float y = rotation[4*g+2], z = rotation[4*g+3];
        float n = rsqrtf(r*r + x*x + y*y + z*z);
        r *= n; x *= n; y *= n; z *= n;
        float R00 = 1.f - 2.f*(y*y + z*z), R01 = 2.f*(x*y - r*z), R02 = 2.f*(x*z + r*y);
        float R10 = 2.f*(x*y + r*z), R11 = 1.f - 2.f*(x*x + z*z), R12 = 2.f*(y*z - r*x);
        float R20 = 2.f*(x*z - r*y), R21 = 2.f*(y*z + r*x), R22 = 1.f - 2.f*(x*x + y*y);

        float pxx = 0.5f*(R00*R00*i0 + R01*R01*i1 + R02*R02*i2);
        float pxy = 0.5f*(R00*R10*i0 + R01*R11*i1 + R02*R12*i2);
        float pxz = 0.5f*(R00*R20*i0 + R01*R21*i1 + R02*R22*i2);
        float pyy = 0.5f*(R10*R10*i0 + R11*R11*i1 + R12*R12*i2);
        float pyz = 0.5f*(R10*R20*i0 + R11*R21*i1 + R12*R22*i2);
        float pzz = 0.5f*(R20*R20*i0 + R21*R21*i1 + R22*R22*i2);

        float op   = 1.f / (1.f + __expf(-opl[g]));
        float lnop = __logf(op);
        // d2 > Tg => w < e^-16 ~ 1.1e-7; dropped total ~2e-3 << 4.1e-2 threshold
        float Tg   = 2.0f * maxs2 * (lnop + 16.0f);

        float* G = gp + (size_t)g * GSTRIDE;
        G[0] = xyz[3*g+0]; G[1] = xyz[3*g+1]; G[2] = xyz[3*g+2]; G[3] = Tg;
        G[4] = pxx; G[5] = pxy; G[6] = pxz; G[7] = pyy;
        G[8] = pyz; G[9] = pzz; G[10] = lnop; G[11] = 0.f;

        const float* sr = sh_rest + (size_t)g * 15;
        G[12] =  SH_C0 * sh_dc[g];
        G[13] = -SH_C1 * sr[0];
        G[14] =  SH_C1 * sr[1];
        G[15] = -SH_C1 * sr[2];
        G[16] =  1.0925484305920792f  * sr[3];
        G[17] = -1.0925484305920792f  * sr[4];
        G[18] =  0.31539156525252005f * sr[5];
        G[19] = -1.0925484305920792f  * sr[6];
        G[20] =  0.5462742152960396f  * sr[7];
        G[21] = -0.5900435899266435f  * sr[8];
        G[22] =  2.890611442640554f   * sr[9];
        G[23] = -0.4570457994644658f  * sr[10];
        G[24] =  0.3731763325901154f  * sr[11];
        G[25] = -0.4570457994644658f  * sr[12];
        G[26] =  1.445305721320277f   * sr[13];
        G[27] = -0.5900435899266435f  * sr[14];
        G[28] = 0.f; G[29] = 0.f; G[30] = 0.f; G[31] = 0.f;
        return;
    }

    // ---- block 0: bin + scan ----
    __shared__ int s_hist[NCELL];
    __shared__ int s_scan[1024];
    #pragma unroll
    for (int i = 0; i < 4; ++i) s_hist[t + i * 1024] = 0;
    __syncthreads();
    for (int p = t; p < N_PTS; p += 1024) {
        float x = pts[3*p+0], y = pts[3*p+1], z = pts[3*p+2];
        int cell = cell_of(x, y, z);
        cellid[p] = cell;
        atomicAdd(&s_hist[cell], 1);
    }
    __syncthreads();
    int b = t * 4;
    int c0 = s_hist[b], c1 = s_hist[b+1], c2 = s_hist[b+2], c3 = s_hist[b+3];
    int s = c0 + c1 + c2 + c3;
    s_scan[t] = s;
    __syncthreads();
    for (int off = 1; off < 1024; off <<= 1) {
        int v = (t >= off) ? s_scan[t - off] : 0;
        __syncthreads();
        s_scan[t] += v;
        __syncthreads();
    }
    int excl = s_scan[t] - s;
    ghist[b]   = excl;
    ghist[b+1] = excl + c0;
    ghist[b+2] = excl + c0 + c1;
    ghist[b+3] = excl + c0 + c1 + c2;
}

// ---------------------------------------------------------------------------
// N2: scatter points into sorted float4 (xyz + bitcast orig index).
// ---------------------------------------------------------------------------
__global__ __launch_bounds__(256) void scatter_kernel(
    const float* __restrict__ pts, const int* __restrict__ cellid,
    int* __restrict__ ghist, float4* __restrict__ spts)
{
    int p = blockIdx.x * 256 + threadIdx.x;
    float x = pts[3*p+0], y = pts[3*p+1], z = pts[3*p+2];
    int pos = atomicAdd(&ghist[cellid[p]], 1);
    spts[pos] = make_float4(x, y, z, __int_as_float(p));
}

// ---------------------------------------------------------------------------
// N3: cull. One block per point-block: AABB over its 256 points ONCE, test
// all 4096 gaussians (16/thread), compact survivors to glist[pb] + gcount.
// (R14-proven; the R14 failure was gauss-side balance, not this kernel.)
// ---------------------------------------------------------------------------
__global__ __launch_bounds__(256) void cull_kernel(
    const float4* __restrict__ spts, const float4* __restrict__ gp4,
    int* __restrict__ glist, int* __restrict__ gcount)
{
    __shared__ float s_min[4][3], s_max[4][3];
    __shared__ int s_n;

    const int tid = threadIdx.x, pb = blockIdx.x;
    float4 P = spts[pb * 256 + tid];
    float px = P.x, py = P.y, pz = P.z;

    float mnx = px, mxx = px, mny = py, mxy = py, mnz = pz, mxz = pz;
    #pragma unroll
    for (int off = 32; off >= 1; off >>= 1) {
        mnx = fminf(mnx, __shfl_xor(mnx, off));
        mxx = fmaxf(mxx, __shfl_xor(mxx, off));
        mny = fminf(mny, __shfl_xor(mny, off));
        mxy = fmaxf(mxy, __shfl_xor(mxy, off));
        mnz = fminf(mnz, __shfl_xor(mnz, off));
        mxz = fmaxf(mxz, __shfl_xor(mxz, off));
    }
    const int wave = tid >> 6;
    if ((tid & 63) == 0) {
        s_min[wave][0] = mnx; s_min[wave][1] = mny; s_min[wave][2] = mnz;
        s_max[wave][0] = mxx; s_max[wave][1] = mxy; s_max[wave][2] = mxz;
    }
    if (tid == 0) s_n = 0;
    __syncthreads();
    const float bmnx = fminf(fminf(s_min[0][0], s_min[1][0]), fminf(s_min[2][0], s_min[3][0]));
    const float bmny = fminf(fminf(s_min[0][1], s_min[1][1]), fminf(s_min[2][1], s_min[3][1]));
    const float bmnz = fminf(fminf(s_min[0][2], s_min[1][2]), fminf(s_min[2][2], s_min[3][2]));
    const float bmxx = fmaxf(fmaxf(s_max[0][0], s_max[1][0]), fmaxf(s_max[2][0], s_max[3][0]));
    const float bmxy = fmaxf(fmaxf(s_max[0][1], s_max[1][1]), fmaxf(s_max[2][1], s_max[3][1]));
    const float bmxz = fmaxf(fmaxf(s_max[0][2], s_max[1][2]), fmaxf(s_max[2][2], s_max[3][2]));

    int* list = glist + (size_t)pb * N_GAUSS;
    #pragma unroll 4
    for (int i = 0; i < 16; ++i) {
        const int g = i * 256 + tid;
        const float4 c = gp4[(size_t)g << 3];
        float ddx = fmaxf(0.f, fmaxf(bmnx - c.x, c.x - bmxx));
        float ddy = fmaxf(0.f, fmaxf(bmny - c.y, c.y - bmxy));
        float ddz = fmaxf(0.f, fmaxf(bmnz - c.z, c.z - bmxz));
        float dd2 = ddx*ddx + ddy*ddy + ddz*ddz;
        if (dd2 <= c.w) {
            int slot = atomicAdd(&s_n, 1);
            list[slot] = g;
        }
    }
    __syncthreads();
    if (tid == 0) gcount[pb] = s_n;
}

// ---------------------------------------------------------------------------
// Eval body for one surviving LDS record (R16-proven math).
// ---------------------------------------------------------------------------
__device__ __forceinline__ void eval_one(
    const float4* R, float dx, float dy, float dz, float d2,
    float& opac, float& sig)
{
    float4 q1 = R[1], q2 = R[2];
    float vx = q1.x*dx + q1.y*dy + q1.z*dz;
    float vy = q1.y*dx + q1.w*dy + q2.x*dz;
    float vz = q1.z*dx + q2.x*dy + q2.y*dz;
    float maha = dx*vx + dy*vy + dz*vz;      // includes the 0.5
    float w = __expf(q2.z - maha);           // op * exp(-0.5*maha)
    opac += w;

    if (__any(w > 1e-9f)) {
        float4 q3 = R[3], q4 = R[4], q5 = R[5], q6 = R[6];
        float rinv = rsqrtf(d2);
        float x = -dx * rinv, y = -dy * rinv, z = -dz * rinv;
        float xx = x*x, yy = y*y, zz = z*z;
        float xy = x*y, yz = y*z, xz = x*z;

        float res = q3.x;
        res += y * q3.y;
        res += z * q3.z;
        res += x * q3.w;
        res += xy * q4.x;
        res += yz * q4.y;
        res += (3.f*zz - 1.f) * q4.z;
        res += xz * q4.w;
        float xxmyy = xx - yy;
        res += xxmyy * q5.x;
        res += y * (3.f*xx - yy) * q5.y;
        res += (xy * z) * q5.z;
        float f5z1 = 5.f*zz - 1.f;
        res += y * f5z1 * q5.w;
        res += z * (5.f*zz - 3.f) * q6.x;
        res += x * f5z1 * q6.y;
        res += z * xxmyy * q6.z;
        res += x * (xxmyy - 3.f*zz) * q6.w;

        sig += w * fmaxf(res, 0.f);
    }
}

// ---------------------------------------------------------------------------
// N4: balanced eval. grid (128, 64). Block = 256 points x the seg-th equal
// slice of its pb's active list (len = ceil(count/64) <= 64). No AABB, no
// cull; stage slice records to LDS -> 2-way pipelined eval -> coalesced
// atomic acc.
// ---------------------------------------------------------------------------
__global__ __launch_bounds__(BLOCK, 4) void gauss_kernel(
    const float4* __restrict__ spts, const float4* __restrict__ gp4,
    const int* __restrict__ glist, const int* __restrict__ gcount,
    float* __restrict__ acc)
{
    __shared__ float4 s_rec[64 * 8];         // 8 KB

    const int tid = threadIdx.x;
    const int pb  = blockIdx.x;
    const int seg = blockIdx.y;
    const int count = gcount[pb];
    const int len = (count + NSLICE - 1) >> 6;     // ceil(count/64), <= 64
    const int j0  = seg * len;
    if (j0 >= count) return;                       // block-uniform exit
    const int n   = min(len, count - j0);

    float4 P = spts[pb * 256 + tid];
    const float px = P.x, py = P.y, pz = P.z;
    const int* __restrict__ list = glist + (size_t)pb * N_GAUSS + j0;

    // stage slice records into LDS: one coalesced burst
    for (int idx = tid; idx < n * 8; idx += BLOCK) {
        int rec = idx >> 3, q = idx & 7;
        s_rec[idx] = gp4[((size_t)list[rec] << 3) + q];
    }
    __syncthreads();

    float opac = 0.f, sig = 0.f;
    for (int j = 0; j < n; j += 2) {
        const bool has1 = (j + 1 < n);
        const float4* A = &s_rec[j * 8];
        const float4* B = &s_rec[(has1 ? j + 1 : j) * 8];

        float4 aq0 = A[0];
        float4 bq0 = B[0];
        float adx = px - aq0.x, ady = py - aq0.y, adz = pz - aq0.z;
        float bdx = px - bq0.x, bdy = py - bq0.y, bdz = pz - bq0.z;
        float ad2 = adx*adx + ady*ady + adz*adz;
        float bd2 = bdx*bdx + bdy*bdy + bdz*bdz;

        if (!__all(ad2 > aq0.w)) eval_one(A, adx, ady, adz, ad2, opac, sig);
        if (has1 && !__all(bd2 > bq0.w)) eval_one(B, bdx, bdy, bdz, bd2, opac, sig);
    }

    // coalesced atomics: wave hits 64 consecutive floats
    const int pos = pb * 256 + tid;
    atomicAdd(&acc[pos], opac);
    atomicAdd(&acc[N_PTS + pos], sig);
}

// ---------------------------------------------------------------------------
// N5: permute acc (sorted index) -> out (original index), plain stores.
// ---------------------------------------------------------------------------
__global__ __launch_bounds__(256) void permute_kernel(
    const float* __restrict__ acc, const float4* __restrict__ spts,
    float* __restrict__ out)
{
    int p = blockIdx.x * 256 + threadIdx.x;
    int orig = __float_as_int(spts[p].w);
    out[orig] = acc[p];
    out[N_PTS + orig] = acc[N_PTS + p];
}

extern "C" void kernel_launch(void* const* d_in, const int* in_sizes, int n_in,
                              void* d_out, int out_size, void* d_ws, size_t ws_size,
                              hipStream_t stream) {
    const float* pts      = (const float*)d_in[0];
    const float* xyz      = (const float*)d_in[3];
    const float* sh_dc    = (const float*)d_in[4];
    const float* sh_rest  = (const float*)d_in[5];
    const float* scaling  = (const float*)d_in[6];
    const float* rotation = (const float*)d_in[7];
    const float* opl      = (const float*)d_in[8];

    float*  out    = (float*)d_out;
    float*  wsf    = (float*)d_ws;
    float*  gp     = wsf + WS_GP;
    int*    ghist  = (int*)(wsf + WS_GHIST);
    int*    cellid = (int*)(wsf + WS_CELLID);
    float4* spts   = (float4*)(wsf + WS_SPTS);
    float*  acc    = wsf + WS_ACC;
    int*    gcount = (int*)(wsf + WS_GCOUNT);
    int*    glist  = (int*)(wsf + WS_GLIST);

    setup_kernel<<<dim3(7), dim3(1024), 0, stream>>>(
        pts, xyz, sh_dc, sh_rest, scaling, rotation, opl, gp, cellid, ghist, acc);
    scatter_kernel<<<dim3(NBLK_PT), dim3(256), 0, stream>>>(pts, cellid, ghist, spts);
    cull_kernel<<<dim3(NBLK_PT), dim3(256), 0, stream>>>(
        spts, (const float4*)gp, glist, gcount);

    dim3 grid(NBLK_PT, NSLICE);
    gauss_kernel<<<grid, dim3(BLOCK), 0, stream>>>(
        spts, (const float4*)gp, glist, gcount, acc);
    permute_kernel<<<dim3(NBLK_PT), dim3(256), 0, stream>>>(acc, spts, out);
}

// Round 18
// 121.211 us; speedup vs baseline: 1.0292x; 1.0292x over previous
//
#include <hip/hip_runtime.h>
#include <hip/hip_bf16.h>

// ---- problem constants ----
#define N_GAUSS 4096
#define N_PTS   32768
#define BLOCK   256
#define NSPLIT  64                  // 64-gaussian segments; grid 128 x 64
#define SEGSZ   (N_GAUSS / NSPLIT)  // 64
#define NBLK_PT 128                 // 128 x 256 = 32768 points
#define GSTRIDE 32                  // floats per packed gaussian = 8 x float4
#define NCELL   4096                // 16^3 morton cells
#define NBIN    16                  // parallel bin blocks

#define SH_C0  0.28209479177387814f
#define SH_C1  0.4886025119029199f

// Workspace layout (float index):
#define WS_GP     0                          // 4096*32 = 131072 floats
#define WS_GHIST  131072                     // int[4096]
#define WS_CELLID 135168                     // int[32768]
#define WS_SPTS   167936                     // float4[32768] (16B aligned)
#define WS_ACC    299008                     // float[65536]
#define WS_HPART  364544                     // int[16*4096] partial histograms
// total 430,080 floats = 1.72 MB

__device__ __forceinline__ int cell_of(float x, float y, float z) {
    int cx = min(15, max(0, (int)((x + 3.2f) * 2.5f)));
    int cy = min(15, max(0, (int)((y + 3.2f) * 2.5f)));
    int cz = min(15, max(0, (int)((z + 3.2f) * 2.5f)));
    int ex = (cx & 1) | ((cx & 2) << 2) | ((cx & 4) << 4) | ((cx & 8) << 6);
    int ey = (cy & 1) | ((cy & 2) << 2) | ((cy & 4) << 4) | ((cy & 8) << 6);
    int ez = (cz & 1) | ((cz & 2) << 2) | ((cz & 4) << 4) | ((cz & 8) << 6);
    return ex | (ey << 1) | (ez << 2);
}

// ---------------------------------------------------------------------------
// N1 (22 blocks x 1024): blocks 0..15 bin 2048 pts each (LDS hist -> partial
// hist dump); blocks 16..19 gaussian prep; blocks 20..21 zero acc.
// Record: q0=(cx,cy,cz,Tg) q1=(pxx,pxy,pxz,pyy) q2=(pyz,pzz,lnop,0)
//         q3..q6 = SH (constants pre-multiplied), q7 = pad
// ---------------------------------------------------------------------------
__global__ __launch_bounds__(1024) void binprep_kernel(
    const float* __restrict__ pts, const float* __restrict__ xyz,
    const float* __restrict__ sh_dc, const float* __restrict__ sh_rest,
    const float* __restrict__ scaling, const float* __restrict__ rotation,
    const float* __restrict__ opl, float* __restrict__ gp,
    int* __restrict__ cellid, int* __restrict__ hpart, float* __restrict__ acc)
{
    const int t = threadIdx.x, bx = blockIdx.x;

    if (bx >= 20) {
        float4* a4 = (float4*)acc;
        int base = (bx - 20) * 1024 * 8 + t;
        #pragma unroll
        for (int i = 0; i < 8; ++i) a4[base + i * 1024] = make_float4(0.f, 0.f, 0.f, 0.f);
        return;
    }
    if (bx >= 16) {
        int g = (bx - 16) * 1024 + t;
        float s0 = scaling[3*g+0], s1 = scaling[3*g+1], s2 = scaling[3*g+2];
        float i0 = __expf(-2.0f * s0);
        float i1 = __expf(-2.0f * s1);
        float i2 = __expf(-2.0f * s2);
        float maxs2 = __expf(2.0f * fmaxf(s0, fmaxf(s1, s2)));

        float r = rotation[4*g+0], x = rotation[4*g+1];
        float y = rotation[4*g+2], z = rotation[4*g+3];
        float n = rsqrtf(r*r + x*x + y*y + z*z);
        r *= n; x *= n; y *= n; z *= n;
        float R00 = 1.f - 2.f*(y*y + z*z), R01 = 2.f*(x*y - r*z), R02 = 2.f*(x*z + r*y);
        float R10 = 2.f*(x*y + r*z), R11 = 1.f - 2.f*(x*x + z*z), R12 = 2.f*(y*z - r*x);
        float R20 = 2.f*(x*z - r*y), R21 = 2.f*(y*z + r*x), R22 = 1.f - 2.f*(x*x + y*y);

        float pxx = 0.5f*(R00*R00*i0 + R01*R01*i1 + R02*R02*i2);
        float pxy = 0.5f*(R00*R10*i0 + R01*R11*i1 + R02*R12*i2);
        float pxz = 0.5f*(R00*R20*i0 + R01*R21*i1 + R02*R22*i2);
        float pyy = 0.5f*(R10*R10*i0 + R11*R11*i1 + R12*R12*i2);
        float pyz = 0.5f*(R10*R20*i0 + R11*R21*i1 + R12*R22*i2);
        float pzz = 0.5f*(R20*R20*i0 + R21*R21*i1 + R22*R22*i2);

        float op   = 1.f / (1.f + __expf(-opl[g]));
        float lnop = __logf(op);
        // d2 > Tg => w < e^-16 ~ 1.1e-7; dropped total ~2e-3 << 4.1e-2 threshold
        float Tg   = 2.0f * maxs2 * (lnop + 16.0f);

        float* G = gp + (size_t)g * GSTRIDE;
        G[0] = xyz[3*g+0]; G[1] = xyz[3*g+1]; G[2] = xyz[3*g+2]; G[3] = Tg;
        G[4] = pxx; G[5] = pxy; G[6] = pxz; G[7] = pyy;
        G[8] = pyz; G[9] = pzz; G[10] = lnop; G[11] = 0.f;

        const float* sr = sh_rest + (size_t)g * 15;
        G[12] =  SH_C0 * sh_dc[g];
        G[13] = -SH_C1 * sr[0];
        G[14] =  SH_C1 * sr[1];
        G[15] = -SH_C1 * sr[2];
        G[16] =  1.0925484305920792f  * sr[3];
        G[17] = -1.0925484305920792f  * sr[4];
        G[18] =  0.31539156525252005f * sr[5];
        G[19] = -1.0925484305920792f  * sr[6];
        G[20] =  0.5462742152960396f  * sr[7];
        G[21] = -0.5900435899266435f  * sr[8];
        G[22] =  2.890611442640554f   * sr[9];
        G[23] = -0.4570457994644658f  * sr[10];
        G[24] =  0.3731763325901154f  * sr[11];
        G[25] = -0.4570457994644658f  * sr[12];
        G[26] =  1.445305721320277f   * sr[13];
        G[27] = -0.5900435899266435f  * sr[14];
        G[28] = 0.f; G[29] = 0.f; G[30] = 0.f; G[31] = 0.f;
        return;
    }

    // ---- bin blocks 0..15: 2048 points each ----
    __shared__ int s_hist[NCELL];
    #pragma unroll
    for (int i = 0; i < 4; ++i) s_hist[t + i * 1024] = 0;
    __syncthreads();
    #pragma unroll
    for (int k = 0; k < 2; ++k) {
        int p = bx * 2048 + k * 1024 + t;
        float x = pts[3*p+0], y = pts[3*p+1], z = pts[3*p+2];
        int cell = cell_of(x, y, z);
        cellid[p] = cell;
        atomicAdd(&s_hist[cell], 1);
    }
    __syncthreads();
    #pragma unroll
    for (int i = 0; i < 4; ++i) {
        int c = t + i * 1024;
        hpart[bx * NCELL + c] = s_hist[c];
    }
}

// ---------------------------------------------------------------------------
// N2: one block sums 16 partial hists per cell + exclusive scan -> ghist.
// ---------------------------------------------------------------------------
__global__ __launch_bounds__(1024) void scan_kernel(
    const int* __restrict__ hpart, int* __restrict__ ghist)
{
    __shared__ int s_scan[1024];
    const int t = threadIdx.x;
    int b = t * 4;
    int c0 = 0, c1 = 0, c2 = 0, c3 = 0;
    #pragma unroll
    for (int k = 0; k < NBIN; ++k) {
        const int* hp = hpart + k * NCELL + b;
        c0 += hp[0]; c1 += hp[1]; c2 += hp[2]; c3 += hp[3];
    }
    int s = c0 + c1 + c2 + c3;
    s_scan[t] = s;
    __syncthreads();
    for (int off = 1; off < 1024; off <<= 1) {
        int v = (t >= off) ? s_scan[t - off] : 0;
        __syncthreads();
        s_scan[t] += v;
        __syncthreads();
    }
    int excl = s_scan[t] - s;
    ghist[b]   = excl;
    ghist[b+1] = excl + c0;
    ghist[b+2] = excl + c0 + c1;
    ghist[b+3] = excl + c0 + c1 + c2;
}

// ---------------------------------------------------------------------------
// N3: scatter points into sorted float4 (xyz + bitcast orig index).
// ---------------------------------------------------------------------------
__global__ __launch_bounds__(256) void scatter_kernel(
    const float* __restrict__ pts, const int* __restrict__ cellid,
    int* __restrict__ ghist, float4* __restrict__ spts)
{
    int p = blockIdx.x * 256 + threadIdx.x;
    float x = pts[3*p+0], y = pts[3*p+1], z = pts[3*p+2];
    int pos = atomicAdd(&ghist[cellid[p]], 1);
    spts[pos] = make_float4(x, y, z, __int_as_float(p));
}

// ---------------------------------------------------------------------------
// Eval body for one surviving LDS record (R16-proven math).
// ---------------------------------------------------------------------------
__device__ __forceinline__ void eval_one(
    const float4* R, float dx, float dy, float dz, float d2,
    float& opac, float& sig)
{
    float4 q1 = R[1], q2 = R[2];
    float vx = q1.x*dx + q1.y*dy + q1.z*dz;
    float vy = q1.y*dx + q1.w*dy + q2.x*dz;
    float vz = q1.z*dx + q2.x*dy + q2.y*dz;
    float maha = dx*vx + dy*vy + dz*vz;      // includes the 0.5
    float w = __expf(q2.z - maha);           // op * exp(-0.5*maha)
    opac += w;

    if (__any(w > 1e-9f)) {
        float4 q3 = R[3], q4 = R[4], q5 = R[5], q6 = R[6];
        float rinv = rsqrtf(d2);
        float x = -dx * rinv, y = -dy * rinv, z = -dz * rinv;
        float xx = x*x, yy = y*y, zz = z*z;
        float xy = x*y, yz = y*z, xz = x*z;

        float res = q3.x;
        res += y * q3.y;
        res += z * q3.z;
        res += x * q3.w;
        res += xy * q4.x;
        res += yz * q4.y;
        res += (3.f*zz - 1.f) * q4.z;
        res += xz * q4.w;
        float xxmyy = xx - yy;
        res += xxmyy * q5.x;
        res += y * (3.f*xx - yy) * q5.y;
        res += (xy * z) * q5.z;
        float f5z1 = 5.f*zz - 1.f;
        res += y * f5z1 * q5.w;
        res += z * (5.f*zz - 3.f) * q6.x;
        res += x * f5z1 * q6.y;
        res += z * xxmyy * q6.z;
        res += x * (xxmyy - 3.f*zz) * q6.w;

        sig += w * fmaxf(res, 0.f);
    }
}

// ---------------------------------------------------------------------------
// N4: main eval (R16-proven). Block = (256 sorted points) x (64-gaussian
// segment). AABB cull -> stage survivors' records to LDS -> 2-way pipelined
// eval -> coalesced atomic acc.
// ---------------------------------------------------------------------------
__global__ __launch_bounds__(BLOCK, 4) void gauss_kernel(
    const float4* __restrict__ spts, const float4* __restrict__ gp4,
    float* __restrict__ acc)
{
    __shared__ float s_min[4][3], s_max[4][3];
    __shared__ int s_nact;
    __shared__ int s_act[SEGSZ];
    __shared__ float4 s_rec[SEGSZ * 8];      // 8 KB

    const int tid = threadIdx.x;
    const int pb  = blockIdx.x;
    const int seg = blockIdx.y;
    float4 P = spts[pb * 256 + tid];
    const float px = P.x, py = P.y, pz = P.z;

    // block AABB
    float mnx = px, mxx = px, mny = py, mxy = py, mnz = pz, mxz = pz;
    #pragma unroll
    for (int off = 32; off >= 1; off >>= 1) {
        mnx = fminf(mnx, __shfl_xor(mnx, off));
        mxx = fmaxf(mxx, __shfl_xor(mxx, off));
        mny = fminf(mny, __shfl_xor(mny, off));
        mxy = fmaxf(mxy, __shfl_xor(mxy, off));
        mnz = fminf(mnz, __shfl_xor(mnz, off));
        mxz = fmaxf(mxz, __shfl_xor(mxz, off));
    }
    const int wave = tid >> 6;
    if ((tid & 63) == 0) {
        s_min[wave][0] = mnx; s_min[wave][1] = mny; s_min[wave][2] = mnz;
        s_max[wave][0] = mxx; s_max[wave][1] = mxy; s_max[wave][2] = mxz;
    }
    if (tid == 0) s_nact = 0;
    __syncthreads();
    const float bmnx = fminf(fminf(s_min[0][0], s_min[1][0]), fminf(s_min[2][0], s_min[3][0]));
    const float bmny = fminf(fminf(s_min[0][1], s_min[1][1]), fminf(s_min[2][1], s_min[3][1]));
    const float bmnz = fminf(fminf(s_min[0][2], s_min[1][2]), fminf(s_min[2][2], s_min[3][2]));
    const float bmxx = fmaxf(fmaxf(s_max[0][0], s_max[1][0]), fmaxf(s_max[2][0], s_max[3][0]));
    const float bmxy = fmaxf(fmaxf(s_max[0][1], s_max[1][1]), fmaxf(s_max[2][1], s_max[3][1]));
    const float bmxz = fmaxf(fmaxf(s_max[0][2], s_max[1][2]), fmaxf(s_max[2][2], s_max[3][2]));

    // conservative cull: threads 0..63 test this segment's 64 gaussians
    if (tid < SEGSZ) {
        const int gg = seg * SEGSZ + tid;
        float4 c = gp4[(size_t)gg << 3];
        float ddx = fmaxf(0.f, fmaxf(bmnx - c.x, c.x - bmxx));
        float ddy = fmaxf(0.f, fmaxf(bmny - c.y, c.y - bmxy));
        float ddz = fmaxf(0.f, fmaxf(bmnz - c.z, c.z - bmxz));
        float dd2 = ddx*ddx + ddy*ddy + ddz*ddz;
        if (dd2 <= c.w) {
            int slot = atomicAdd(&s_nact, 1);
            s_act[slot] = gg;
        }
    }
    __syncthreads();
    const int nact = s_nact;
    if (nact == 0) return;

    // stage survivors' records into LDS: one coalesced burst
    for (int idx = tid; idx < nact * 8; idx += BLOCK) {
        int rec = idx >> 3, q = idx & 7;
        s_rec[idx] = gp4[((size_t)s_act[rec] << 3) + q];
    }
    __syncthreads();

    float opac = 0.f, sig = 0.f;
    for (int j = 0; j < nact; j += 2) {
        const bool has1 = (j + 1 < nact);
        const float4* A = &s_rec[j * 8];
        const float4* B = &s_rec[(has1 ? j + 1 : j) * 8];

        float4 aq0 = A[0];
        float4 bq0 = B[0];
        float adx = px - aq0.x, ady = py - aq0.y, adz = pz - aq0.z;
        float bdx = px - bq0.x, bdy = py - bq0.y, bdz = pz - bq0.z;
        float ad2 = adx*adx + ady*ady + adz*adz;
        float bd2 = bdx*bdx + bdy*bdy + bdz*bdz;

        if (!__all(ad2 > aq0.w)) eval_one(A, adx, ady, adz, ad2, opac, sig);
        if (has1 && !__all(bd2 > bq0.w)) eval_one(B, bdx, bdy, bdz, bd2, opac, sig);
    }

    // coalesced atomics: wave hits 64 consecutive floats
    const int pos = pb * 256 + tid;
    atomicAdd(&acc[pos], opac);
    atomicAdd(&acc[N_PTS + pos], sig);
}

// ---------------------------------------------------------------------------
// N5: permute acc (sorted index) -> out (original index), plain stores.
// ---------------------------------------------------------------------------
__global__ __launch_bounds__(256) void permute_kernel(
    const float* __restrict__ acc, const float4* __restrict__ spts,
    float* __restrict__ out)
{
    int p = blockIdx.x * 256 + threadIdx.x;
    int orig = __float_as_int(spts[p].w);
    out[orig] = acc[p];
    out[N_PTS + orig] = acc[N_PTS + p];
}

extern "C" void kernel_launch(void* const* d_in, const int* in_sizes, int n_in,
                              void* d_out, int out_size, void* d_ws, size_t ws_size,
                              hipStream_t stream) {
    const float* pts      = (const float*)d_in[0];
    const float* xyz      = (const float*)d_in[3];
    const float* sh_dc    = (const float*)d_in[4];
    const float* sh_rest  = (const float*)d_in[5];
    const float* scaling  = (const float*)d_in[6];
    const float* rotation = (const float*)d_in[7];
    const float* opl      = (const float*)d_in[8];

    float*  out    = (float*)d_out;
    float*  wsf    = (float*)d_ws;
    float*  gp     = wsf + WS_GP;
    int*    ghist  = (int*)(wsf + WS_GHIST);
    int*    cellid = (int*)(wsf + WS_CELLID);
    float4* spts   = (float4*)(wsf + WS_SPTS);
    float*  acc    = wsf + WS_ACC;
    int*    hpart  = (int*)(wsf + WS_HPART);

    binprep_kernel<<<dim3(22), dim3(1024), 0, stream>>>(
        pts, xyz, sh_dc, sh_rest, scaling, rotation, opl, gp, cellid, hpart, acc);
    scan_kernel<<<dim3(1), dim3(1024), 0, stream>>>(hpart, ghist);
    scatter_kernel<<<dim3(NBLK_PT), dim3(256), 0, stream>>>(pts, cellid, ghist, spts);

    dim3 grid(NBLK_PT, NSPLIT);
    gauss_kernel<<<grid, dim3(BLOCK), 0, stream>>>(spts, (const float4*)gp, acc);
    permute_kernel<<<dim3(NBLK_PT), dim3(256), 0, stream>>>(acc, spts, out);
}

// Round 19
// 118.605 us; speedup vs baseline: 1.0518x; 1.0220x over previous
//
#include <hip/hip_runtime.h>
#include <hip/hip_bf16.h>

// ---- problem constants ----
#define N_GAUSS 4096
#define N_PTS   32768
#define BLOCK   256
#define NSPLIT  32                  // 128-gaussian segments; grid 128 x 32
#define SEGSZ   (N_GAUSS / NSPLIT)  // 128
#define NBLK_PT 128                 // 128 x 256 = 32768 points
#define GSTRIDE 32                  // floats per packed gaussian = 8 x float4
#define NCELL   4096                // 16^3 morton cells
#define NBIN    16                  // parallel bin blocks

#define SH_C0  0.28209479177387814f
#define SH_C1  0.4886025119029199f

// Workspace layout (float index):
#define WS_GP     0                          // 4096*32 = 131072 floats
#define WS_GHIST  131072                     // int[4096]
#define WS_CELLID 135168                     // int[32768]
#define WS_SPTS   167936                     // float4[32768] (16B aligned)
#define WS_ACC    299008                     // float[65536]
#define WS_HPART  364544                     // int[16*4096] partial histograms
// total 430,080 floats = 1.72 MB

__device__ __forceinline__ int cell_of(float x, float y, float z) {
    int cx = min(15, max(0, (int)((x + 3.2f) * 2.5f)));
    int cy = min(15, max(0, (int)((y + 3.2f) * 2.5f)));
    int cz = min(15, max(0, (int)((z + 3.2f) * 2.5f)));
    int ex = (cx & 1) | ((cx & 2) << 2) | ((cx & 4) << 4) | ((cx & 8) << 6);
    int ey = (cy & 1) | ((cy & 2) << 2) | ((cy & 4) << 4) | ((cy & 8) << 6);
    int ez = (cz & 1) | ((cz & 2) << 2) | ((cz & 4) << 4) | ((cz & 8) << 6);
    return ex | (ey << 1) | (ez << 2);
}

// ---------------------------------------------------------------------------
// N1 (22 blocks x 1024): blocks 0..15 bin 2048 pts each (LDS hist -> partial
// hist dump); blocks 16..19 gaussian prep; blocks 20..21 zero acc. (R18)
// Record: q0=(cx,cy,cz,Tg) q1=(pxx,pxy,pxz,pyy) q2=(pyz,pzz,lnop,0)
//         q3..q6 = SH (constants pre-multiplied), q7 = pad
// ---------------------------------------------------------------------------
__global__ __launch_bounds__(1024) void binprep_kernel(
    const float* __restrict__ pts, const float* __restrict__ xyz,
    const float* __restrict__ sh_dc, const float* __restrict__ sh_rest,
    const float* __restrict__ scaling, const float* __restrict__ rotation,
    const float* __restrict__ opl, float* __restrict__ gp,
    int* __restrict__ cellid, int* __restrict__ hpart, float* __restrict__ acc)
{
    const int t = threadIdx.x, bx = blockIdx.x;

    if (bx >= 20) {
        float4* a4 = (float4*)acc;
        int base = (bx - 20) * 1024 * 8 + t;
        #pragma unroll
        for (int i = 0; i < 8; ++i) a4[base + i * 1024] = make_float4(0.f, 0.f, 0.f, 0.f);
        return;
    }
    if (bx >= 16) {
        int g = (bx - 16) * 1024 + t;
        float s0 = scaling[3*g+0], s1 = scaling[3*g+1], s2 = scaling[3*g+2];
        float i0 = __expf(-2.0f * s0);
        float i1 = __expf(-2.0f * s1);
        float i2 = __expf(-2.0f * s2);
        float maxs2 = __expf(2.0f * fmaxf(s0, fmaxf(s1, s2)));

        float r = rotation[4*g+0], x = rotation[4*g+1];
        float y = rotation[4*g+2], z = rotation[4*g+3];
        float n = rsqrtf(r*r + x*x + y*y + z*z);
        r *= n; x *= n; y *= n; z *= n;
        float R00 = 1.f - 2.f*(y*y + z*z), R01 = 2.f*(x*y - r*z), R02 = 2.f*(x*z + r*y);
        float R10 = 2.f*(x*y + r*z), R11 = 1.f - 2.f*(x*x + z*z), R12 = 2.f*(y*z - r*x);
        float R20 = 2.f*(x*z - r*y), R21 = 2.f*(y*z + r*x), R22 = 1.f - 2.f*(x*x + y*y);

        float pxx = 0.5f*(R00*R00*i0 + R01*R01*i1 + R02*R02*i2);
        float pxy = 0.5f*(R00*R10*i0 + R01*R11*i1 + R02*R12*i2);
        float pxz = 0.5f*(R00*R20*i0 + R01*R21*i1 + R02*R22*i2);
        float pyy = 0.5f*(R10*R10*i0 + R11*R11*i1 + R12*R12*i2);
        float pyz = 0.5f*(R10*R20*i0 + R11*R21*i1 + R12*R22*i2);
        float pzz = 0.5f*(R20*R20*i0 + R21*R21*i1 + R22*R22*i2);

        float op   = 1.f / (1.f + __expf(-opl[g]));
        float lnop = __logf(op);
        // d2 > Tg => w < e^-16 ~ 1.1e-7; dropped total ~2e-3 << 4.1e-2 threshold
        float Tg   = 2.0f * maxs2 * (lnop + 16.0f);

        float* G = gp + (size_t)g * GSTRIDE;
        G[0] = xyz[3*g+0]; G[1] = xyz[3*g+1]; G[2] = xyz[3*g+2]; G[3] = Tg;
        G[4] = pxx; G[5] = pxy; G[6] = pxz; G[7] = pyy;
        G[8] = pyz; G[9] = pzz; G[10] = lnop; G[11] = 0.f;

        const float* sr = sh_rest + (size_t)g * 15;
        G[12] =  SH_C0 * sh_dc[g];
        G[13] = -SH_C1 * sr[0];
        G[14] =  SH_C1 * sr[1];
        G[15] = -SH_C1 * sr[2];
        G[16] =  1.0925484305920792f  * sr[3];
        G[17] = -1.0925484305920792f  * sr[4];
        G[18] =  0.31539156525252005f * sr[5];
        G[19] = -1.0925484305920792f  * sr[6];
        G[20] =  0.5462742152960396f  * sr[7];
        G[21] = -0.5900435899266435f  * sr[8];
        G[22] =  2.890611442640554f   * sr[9];
        G[23] = -0.4570457994644658f  * sr[10];
        G[24] =  0.3731763325901154f  * sr[11];
        G[25] = -0.4570457994644658f  * sr[12];
        G[26] =  1.445305721320277f   * sr[13];
        G[27] = -0.5900435899266435f  * sr[14];
        G[28] = 0.f; G[29] = 0.f; G[30] = 0.f; G[31] = 0.f;
        return;
    }

    // ---- bin blocks 0..15: 2048 points each ----
    __shared__ int s_hist[NCELL];
    #pragma unroll
    for (int i = 0; i < 4; ++i) s_hist[t + i * 1024] = 0;
    __syncthreads();
    #pragma unroll
    for (int k = 0; k < 2; ++k) {
        int p = bx * 2048 + k * 1024 + t;
        float x = pts[3*p+0], y = pts[3*p+1], z = pts[3*p+2];
        int cell = cell_of(x, y, z);
        cellid[p] = cell;
        atomicAdd(&s_hist[cell], 1);
    }
    __syncthreads();
    #pragma unroll
    for (int i = 0; i < 4; ++i) {
        int c = t + i * 1024;
        hpart[bx * NCELL + c] = s_hist[c];
    }
}

// ---------------------------------------------------------------------------
// N2: one block sums 16 partial hists per cell + exclusive scan -> ghist.
// ---------------------------------------------------------------------------
__global__ __launch_bounds__(1024) void scan_kernel(
    const int* __restrict__ hpart, int* __restrict__ ghist)
{
    __shared__ int s_scan[1024];
    const int t = threadIdx.x;
    int b = t * 4;
    int c0 = 0, c1 = 0, c2 = 0, c3 = 0;
    #pragma unroll
    for (int k = 0; k < NBIN; ++k) {
        const int* hp = hpart + k * NCELL + b;
        c0 += hp[0]; c1 += hp[1]; c2 += hp[2]; c3 += hp[3];
    }
    int s = c0 + c1 + c2 + c3;
    s_scan[t] = s;
    __syncthreads();
    for (int off = 1; off < 1024; off <<= 1) {
        int v = (t >= off) ? s_scan[t - off] : 0;
        __syncthreads();
        s_scan[t] += v;
        __syncthreads();
    }
    int excl = s_scan[t] - s;
    ghist[b]   = excl;
    ghist[b+1] = excl + c0;
    ghist[b+2] = excl + c0 + c1;
    ghist[b+3] = excl + c0 + c1 + c2;
}

// ---------------------------------------------------------------------------
// N3: scatter points into sorted float4 (xyz + bitcast orig index).
// ---------------------------------------------------------------------------
__global__ __launch_bounds__(256) void scatter_kernel(
    const float* __restrict__ pts, const int* __restrict__ cellid,
    int* __restrict__ ghist, float4* __restrict__ spts)
{
    int p = blockIdx.x * 256 + threadIdx.x;
    float x = pts[3*p+0], y = pts[3*p+1], z = pts[3*p+2];
    int pos = atomicAdd(&ghist[cellid[p]], 1);
    spts[pos] = make_float4(x, y, z, __int_as_float(p));
}

// ---------------------------------------------------------------------------
// Eval body for one surviving LDS record (R16-proven math).
// ---------------------------------------------------------------------------
__device__ __forceinline__ void eval_one(
    const float4* R, float dx, float dy, float dz, float d2,
    float& opac, float& sig)
{
    float4 q1 = R[1], q2 = R[2];
    float vx = q1.x*dx + q1.y*dy + q1.z*dz;
    float vy = q1.y*dx + q1.w*dy + q2.x*dz;
    float vz = q1.z*dx + q2.x*dy + q2.y*dz;
    float maha = dx*vx + dy*vy + dz*vz;      // includes the 0.5
    float w = __expf(q2.z - maha);           // op * exp(-0.5*maha)
    opac += w;

    if (__any(w > 1e-9f)) {
        float4 q3 = R[3], q4 = R[4], q5 = R[5], q6 = R[6];
        float rinv = rsqrtf(d2);
        float x = -dx * rinv, y = -dy * rinv, z = -dz * rinv;
        float xx = x*x, yy = y*y, zz = z*z;
        float xy = x*y, yz = y*z, xz = x*z;

        float res = q3.x;
        res += y * q3.y;
        res += z * q3.z;
        res += x * q3.w;
        res += xy * q4.x;
        res += yz * q4.y;
        res += (3.f*zz - 1.f) * q4.z;
        res += xz * q4.w;
        float xxmyy = xx - yy;
        res += xxmyy * q5.x;
        res += y * (3.f*xx - yy) * q5.y;
        res += (xy * z) * q5.z;
        float f5z1 = 5.f*zz - 1.f;
        res += y * f5z1 * q5.w;
        res += z * (5.f*zz - 3.f) * q6.x;
        res += x * f5z1 * q6.y;
        res += z * xxmyy * q6.z;
        res += x * (xxmyy - 3.f*zz) * q6.w;

        sig += w * fmaxf(res, 0.f);
    }
}

// ---------------------------------------------------------------------------
// N4: main eval. Block = (256 sorted points) x (128-gaussian segment).
// Half the blocks of R18 (4096): fixed per-block work halves; staging LDS
// grows to 16 KB (max 128 records), still 4 blocks/CU.
// ---------------------------------------------------------------------------
__global__ __launch_bounds__(BLOCK, 4) void gauss_kernel(
    const float4* __restrict__ spts, const float4* __restrict__ gp4,
    float* __restrict__ acc)
{
    __shared__ float s_min[4][3], s_max[4][3];
    __shared__ int s_nact;
    __shared__ int s_act[SEGSZ];
    __shared__ float4 s_rec[SEGSZ * 8];      // 16 KB

    const int tid = threadIdx.x;
    const int pb  = blockIdx.x;
    const int seg = blockIdx.y;
    float4 P = spts[pb * 256 + tid];
    const float px = P.x, py = P.y, pz = P.z;

    // block AABB
    float mnx = px, mxx = px, mny = py, mxy = py, mnz = pz, mxz = pz;
    #pragma unroll
    for (int off = 32; off >= 1; off >>= 1) {
        mnx = fminf(mnx, __shfl_xor(mnx, off));
        mxx = fmaxf(mxx, __shfl_xor(mxx, off));
        mny = fminf(mny, __shfl_xor(mny, off));
        mxy = fmaxf(mxy, __shfl_xor(mxy, off));
        mnz = fminf(mnz, __shfl_xor(mnz, off));
        mxz = fmaxf(mxz, __shfl_xor(mxz, off));
    }
    const int wave = tid >> 6;
    if ((tid & 63) == 0) {
        s_min[wave][0] = mnx; s_min[wave][1] = mny; s_min[wave][2] = mnz;
        s_max[wave][0] = mxx; s_max[wave][1] = mxy; s_max[wave][2] = mxz;
    }
    if (tid == 0) s_nact = 0;
    __syncthreads();
    const float bmnx = fminf(fminf(s_min[0][0], s_min[1][0]), fminf(s_min[2][0], s_min[3][0]));
    const float bmny = fminf(fminf(s_min[0][1], s_min[1][1]), fminf(s_min[2][1], s_min[3][1]));
    const float bmnz = fminf(fminf(s_min[0][2], s_min[1][2]), fminf(s_min[2][2], s_min[3][2]));
    const float bmxx = fmaxf(fmaxf(s_max[0][0], s_max[1][0]), fmaxf(s_max[2][0], s_max[3][0]));
    const float bmxy = fmaxf(fmaxf(s_max[0][1], s_max[1][1]), fmaxf(s_max[2][1], s_max[3][1]));
    const float bmxz = fmaxf(fmaxf(s_max[0][2], s_max[1][2]), fmaxf(s_max[2][2], s_max[3][2]));

    // conservative cull: threads 0..127 test this segment's 128 gaussians
    if (tid < SEGSZ) {
        const int gg = seg * SEGSZ + tid;
        float4 c = gp4[(size_t)gg << 3];
        float ddx = fmaxf(0.f, fmaxf(bmnx - c.x, c.x - bmxx));
        float ddy = fmaxf(0.f, fmaxf(bmny - c.y, c.y - bmxy));
        float ddz = fmaxf(0.f, fmaxf(bmnz - c.z, c.z - bmxz));
        float dd2 = ddx*ddx + ddy*ddy + ddz*ddz;
        if (dd2 <= c.w) {
            int slot = atomicAdd(&s_nact, 1);
            s_act[slot] = gg;
        }
    }
    __syncthreads();
    const int nact = s_nact;
    if (nact == 0) return;

    // stage survivors' records into LDS: one coalesced burst
    for (int idx = tid; idx < nact * 8; idx += BLOCK) {
        int rec = idx >> 3, q = idx & 7;
        s_rec[idx] = gp4[((size_t)s_act[rec] << 3) + q];
    }
    __syncthreads();

    float opac = 0.f, sig = 0.f;
    for (int j = 0; j < nact; j += 2) {
        const bool has1 = (j + 1 < nact);
        const float4* A = &s_rec[j * 8];
        const float4* B = &s_rec[(has1 ? j + 1 : j) * 8];

        float4 aq0 = A[0];
        float4 bq0 = B[0];
        float adx = px - aq0.x, ady = py - aq0.y, adz = pz - aq0.z;
        float bdx = px - bq0.x, bdy = py - bq0.y, bdz = pz - bq0.z;
        float ad2 = adx*adx + ady*ady + adz*adz;
        float bd2 = bdx*bdx + bdy*bdy + bdz*bdz;

        if (!__all(ad2 > aq0.w)) eval_one(A, adx, ady, adz, ad2, opac, sig);
        if (has1 && !__all(bd2 > bq0.w)) eval_one(B, bdx, bdy, bdz, bd2, opac, sig);
    }

    // coalesced atomics: wave hits 64 consecutive floats
    const int pos = pb * 256 + tid;
    atomicAdd(&acc[pos], opac);
    atomicAdd(&acc[N_PTS + pos], sig);
}

// ---------------------------------------------------------------------------
// N5: permute acc (sorted index) -> out (original index), plain stores.
// ---------------------------------------------------------------------------
__global__ __launch_bounds__(256) void permute_kernel(
    const float* __restrict__ acc, const float4* __restrict__ spts,
    float* __restrict__ out)
{
    int p = blockIdx.x * 256 + threadIdx.x;
    int orig = __float_as_int(spts[p].w);
    out[orig] = acc[p];
    out[N_PTS + orig] = acc[N_PTS + p];
}

extern "C" void kernel_launch(void* const* d_in, const int* in_sizes, int n_in,
                              void* d_out, int out_size, void* d_ws, size_t ws_size,
                              hipStream_t stream) {
    const float* pts      = (const float*)d_in[0];
    const float* xyz      = (const float*)d_in[3];
    const float* sh_dc    = (const float*)d_in[4];
    const float* sh_rest  = (const float*)d_in[5];
    const float* scaling  = (const float*)d_in[6];
    const float* rotation = (const float*)d_in[7];
    const float* opl      = (const float*)d_in[8];

    float*  out    = (float*)d_out;
    float*  wsf    = (float*)d_ws;
    float*  gp     = wsf + WS_GP;
    int*    ghist  = (int*)(wsf + WS_GHIST);
    int*    cellid = (int*)(wsf + WS_CELLID);
    float4* spts   = (float4*)(wsf + WS_SPTS);
    float*  acc    = wsf + WS_ACC;
    int*    hpart  = (int*)(wsf + WS_HPART);

    binprep_kernel<<<dim3(22), dim3(1024), 0, stream>>>(
        pts, xyz, sh_dc, sh_rest, scaling, rotation, opl, gp, cellid, hpart, acc);
    scan_kernel<<<dim3(1), dim3(1024), 0, stream>>>(hpart, ghist);
    scatter_kernel<<<dim3(NBLK_PT), dim3(256), 0, stream>>>(pts, cellid, ghist, spts);

    dim3 grid(NBLK_PT, NSPLIT);
    gauss_kernel<<<grid, dim3(BLOCK), 0, stream>>>(spts, (const float4*)gp, acc);
    permute_kernel<<<dim3(NBLK_PT), dim3(256), 0, stream>>>(acc, spts, out);
}